// Round 6
// baseline (39661.105 us; speedup 1.0000x reference)
//
#include <hip/hip_runtime.h>
#include <hip/hip_fp16.h>
#include <stdint.h>

#define B_  512
#define S_  512
#define IN_ 118
#define H1_ 256
#define H2_ 128

typedef __attribute__((ext_vector_type(8))) short frag8;    // 8 fp16 = 4 VGPRs
typedef __attribute__((ext_vector_type(4))) float facc4;    // MFMA accumulator
typedef __attribute__((ext_vector_type(4))) unsigned int uv4;
typedef unsigned short u16;
typedef unsigned int   u32;

#define SC1 2048.0f           // 2^11
#define SC2 4194304.0f        // 2^22
#define ISC1 (1.0f/2048.0f)
#define ISC2 (1.0f/4194304.0f)

// 3-way scaled fp16 split: v ~= hi + mid/2^11 + lo/2^22, residual ~2^-33*v.
// Scaled planes are normal-range fp16 (no denormal reliance).
__device__ __forceinline__ void split3(float v, u16& a, u16& b, u16& c) {
    __half h0 = __float2half(v);
    float  f0 = __half2float(h0);
    float  r1 = v - f0;
    __half h1 = __float2half(r1 * SC1);
    float  r2 = r1 - __half2float(h1) * ISC1;
    __half h2 = __float2half(r2 * SC2);
    a = *(u16*)&h0; b = *(u16*)&h1; c = *(u16*)&h2;
}
__device__ __forceinline__ float sigm_(float x) { return 1.f / (1.f + expf(-x)); }

// ---------------- ws layout (bytes) ----------------
// 0        w1a 786432   fp16 [64 nt][12 kf][64 lane][8]  (hi)
// 786432   w1b 786432   (mid*2^11)
// 1572864  w1c 786432   (lo*2^22)
// 2359296  w2a 393216   fp16 [32 nt][12 kf][64 lane][8]
// 2752512  w2b 393216
// 3145728  w2c 393216
// 3538944  c1s 524288   fp32 [512][256]
// 4063232  h1a 262144   u16  [512][256]  (+h1b,h1c)
// 4849664  c2s 262144   fp32 [512][128]
// 5111808  h2a 131072   (+h2b,h2c)
// 5505024  ring1 u32 [2][32][Tc][16][256]  (mid<<16|hi)
//          ring2 u16 [2][32][Tc][16][256]  (lo)
// ---------------------------------------------------

__global__ void prep_weights(const float* __restrict__ Wf1, const float* __restrict__ Wi1,
                             const float* __restrict__ Wg1, const float* __restrict__ Wo1,
                             const float* __restrict__ Wf2, const float* __restrict__ Wi2,
                             const float* __restrict__ Wg2, const float* __restrict__ Wo2,
                             u16* __restrict__ w1a, u16* __restrict__ w1b, u16* __restrict__ w1c,
                             u16* __restrict__ w2a, u16* __restrict__ w2b, u16* __restrict__ w2c) {
    int idx = blockIdx.x * 256 + threadIdx.x;
    if (idx >= 589824) return;
    if (idx < 393216) {
        int j  = idx & 7;
        int L  = (idx >> 3) & 63;
        int fr = idx >> 9;            // nt*12 + kf
        int kf = fr % 12, nt = fr / 12;
        int khat = kf * 32 + (L >> 4) * 8 + j;   // B[k][n]: k = quad*8+j
        int n    = nt * 16 + (L & 15);           //          n = lane&15
        const float* Wg[4] = {Wf1, Wi1, Wg1, Wo1};
        float v = 0.f;
        if (khat < 128) {
            if (khat < IN_) v = Wg[n >> 8][(n & 255) * 374 + khat];      // x part
        } else {
            v = Wg[n >> 8][(n & 255) * 374 + (khat - 10)];               // h part
        }
        u16 a, b, c; split3(v, a, b, c);
        w1a[idx] = a; w1b[idx] = b; w1c[idx] = c;
    } else {
        int i2 = idx - 393216;
        int j  = i2 & 7;
        int L  = (i2 >> 3) & 63;
        int fr = i2 >> 9;
        int kf = fr % 12, nt = fr / 12;
        int khat = kf * 32 + (L >> 4) * 8 + j;
        int n    = nt * 16 + (L & 15);
        const float* Wg[4] = {Wf2, Wi2, Wg2, Wo2};
        float v = Wg[n >> 7][(n & 127) * 384 + khat];
        u16 a, b, c; split3(v, a, b, c);
        w2a[i2] = a; w2b[i2] = b; w2c[i2] = c;
    }
}

// Dynamic LDS (38784 B):
//  0      combA : u16 [16][392]  12544 B  (hi;  pitch 392: 16B-aligned, odd/16 kills bank conflicts)
//  12544  combB : u16 [16][392]  (mid*2^11)
//  25088  combC : u16 [16][392]  (lo*2^22)
//  37632  sS[16][8], sQ[16][8], sMu[16], sRs[16]  floats (1152 B)

__global__ __launch_bounds__(512, 1) void lstm_chunk(
    const float* __restrict__ x,
    const float* __restrict__ bf1, const float* __restrict__ bi1,
    const float* __restrict__ bg1, const float* __restrict__ bo1,
    const float* __restrict__ bf2, const float* __restrict__ bi2,
    const float* __restrict__ bg2, const float* __restrict__ bo2,
    const float* __restrict__ gamma1, const float* __restrict__ beta1,
    const float* __restrict__ gamma2, const float* __restrict__ beta2,
    const u16* __restrict__ w1a, const u16* __restrict__ w1b, const u16* __restrict__ w1c,
    const u16* __restrict__ w2a, const u16* __restrict__ w2b, const u16* __restrict__ w2c,
    u32* __restrict__ ring1, u16* __restrict__ ring2,
    float* __restrict__ c1s, u16* __restrict__ h1a, u16* __restrict__ h1b, u16* __restrict__ h1c,
    float* __restrict__ c2s, u16* __restrict__ h2a, u16* __restrict__ h2b, u16* __restrict__ h2c,
    int t0, int Tc, float* __restrict__ out)
{
    extern __shared__ char smem[];
    const int tid  = threadIdx.x;
    const int w    = tid >> 6;
    const int lane = tid & 63;
    const int q    = lane >> 4;
    const int cc   = lane & 15;
    const int bid  = blockIdx.x;

    u16*   combA = (u16*)smem;
    u16*   combB = (u16*)(smem + 12544);
    u16*   combC = (u16*)(smem + 25088);
    float* sS    = (float*)(smem + 37632);
    float* sQ    = sS + 128;
    float* sMu   = sQ + 128;
    float* sRs   = sMu + 16;

    if (bid < 32) {
        // ============ PHASE 1 : layer 1, chunk [t0, t0+Tc) ============
        if (t0 >= S_) return;
        const int tile = bid, b0 = tile * 16;

        // regs: hi-weights kf 0..1 resident
        frag8 wregH[8][2];
        #pragma unroll
        for (int k = 0; k < 8; ++k) {
            int nt = w + 8 * k;
            #pragma unroll
            for (int kf = 0; kf < 2; ++kf)
                wregH[k][kf] = *(const frag8*)&w1a[(((size_t)nt * 12 + kf) * 64 + lane) * 8];
        }
        float bz[8];
        #pragma unroll
        for (int k = 0; k < 8; ++k) {
            int n = (w + 8 * k) * 16 + cc;
            const float* bp = (n < 256) ? bf1 : (n < 512) ? bi1 : (n < 768) ? bg1 : bo1;
            bz[k] = bp[n & 255];
        }
        const int u0 = w * 16 + cc, u1 = u0 + 128;
        const float g0 = gamma1[u0], g1 = gamma1[u1];
        const float be0 = beta1[u0], be1 = beta1[u1];

        if (t0 == 0) {
            for (int i = tid; i < 4096; i += 512) {
                int row = i >> 8, col = i & 255;
                combA[row * 392 + 128 + col] = 0;
                combB[row * 392 + 128 + col] = 0;
                combC[row * 392 + 128 + col] = 0;
            }
        } else {
            for (int i = tid; i < 4096; i += 512) {
                int row = i >> 8, col = i & 255;
                size_t g = (size_t)(b0 + row) * 256 + col;
                combA[row * 392 + 128 + col] = __builtin_nontemporal_load(&h1a[g]);
                combB[row * 392 + 128 + col] = __builtin_nontemporal_load(&h1b[g]);
                combC[row * 392 + 128 + col] = __builtin_nontemporal_load(&h1c[g]);
            }
        }
        float cst[2][4];
        #pragma unroll
        for (int uu = 0; uu < 2; ++uu)
            #pragma unroll
            for (int r = 0; r < 4; ++r) {
                int m = q * 4 + r, u = (w + 8 * uu) * 16 + cc;
                cst[uu][r] = (t0 == 0) ? 0.f
                    : __builtin_nontemporal_load(&c1s[(size_t)(b0 + m) * 256 + u]);
            }
        __syncthreads();

        const int par = (t0 / Tc) & 1;
        u32* myr1 = ring1 + (((size_t)par * 32 + tile) * Tc) * 4096;
        u16* myr2 = ring2 + (((size_t)par * 32 + tile) * Tc) * 4096;

        for (int lt = 0; lt < Tc; ++lt) {
            const int t = t0 + lt;
            // stage x_t (3-way split) -> comb cols [0,128)
            for (int i = tid; i < 2048; i += 512) {
                int row = i >> 7, col = i & 127;
                float v = (col < IN_)
                    ? __builtin_nontemporal_load(&x[((size_t)(b0 + row) * S_ + t) * IN_ + col])
                    : 0.f;
                u16 a, b, c; split3(v, a, b, c);
                combA[row * 392 + col] = a;
                combB[row * 392 + col] = b;
                combC[row * 392 + col] = c;
            }
            __syncthreads();

            facc4 g0a[8], g1a[8], g2a[8];
            #pragma unroll
            for (int k = 0; k < 8; ++k) {
                g0a[k] = (facc4){0.f,0.f,0.f,0.f};
                g1a[k] = (facc4){0.f,0.f,0.f,0.f};
                g2a[k] = (facc4){0.f,0.f,0.f,0.f};
            }
            #pragma unroll
            for (int kf = 0; kf < 12; ++kf) {
                frag8 aH = *(frag8*)&combA[cc * 392 + kf * 32 + q * 8];
                frag8 aM = *(frag8*)&combB[cc * 392 + kf * 32 + q * 8];
                frag8 aL = *(frag8*)&combC[cc * 392 + kf * 32 + q * 8];
                #pragma unroll
                for (int k = 0; k < 8; ++k) {
                    size_t base = (((size_t)(w + 8 * k) * 12 + kf) * 64 + lane) * 8;
                    frag8 bH = (kf < 2) ? wregH[k][kf] : *(const frag8*)&w1a[base];
                    frag8 bM = *(const frag8*)&w1b[base];
                    frag8 bL = *(const frag8*)&w1c[base];
                    g0a[k] = __builtin_amdgcn_mfma_f32_16x16x32_f16(aH, bH, g0a[k], 0, 0, 0);
                    g1a[k] = __builtin_amdgcn_mfma_f32_16x16x32_f16(aH, bM, g1a[k], 0, 0, 0);
                    g1a[k] = __builtin_amdgcn_mfma_f32_16x16x32_f16(aM, bH, g1a[k], 0, 0, 0);
                    g2a[k] = __builtin_amdgcn_mfma_f32_16x16x32_f16(aH, bL, g2a[k], 0, 0, 0);
                    g2a[k] = __builtin_amdgcn_mfma_f32_16x16x32_f16(aM, bM, g2a[k], 0, 0, 0);
                    g2a[k] = __builtin_amdgcn_mfma_f32_16x16x32_f16(aL, bH, g2a[k], 0, 0, 0);
                }
            }
            float hv[2][4];
            #pragma unroll
            for (int uu = 0; uu < 2; ++uu)
                #pragma unroll
                for (int r = 0; r < 4; ++r) {
                    float zf = g0a[0+uu][r] + g1a[0+uu][r]*ISC1 + g2a[0+uu][r]*ISC2 + bz[0+uu];
                    float zi = g0a[2+uu][r] + g1a[2+uu][r]*ISC1 + g2a[2+uu][r]*ISC2 + bz[2+uu];
                    float zg = g0a[4+uu][r] + g1a[4+uu][r]*ISC1 + g2a[4+uu][r]*ISC2 + bz[4+uu];
                    float zo = g0a[6+uu][r] + g1a[6+uu][r]*ISC1 + g2a[6+uu][r]*ISC2 + bz[6+uu];
                    float c  = sigm_(zf) * cst[uu][r] + sigm_(zi) * tanhf(zg);
                    cst[uu][r] = c;
                    hv[uu][r]  = sigm_(zo) * tanhf(c);
                }
            float s_[4], q_[4];
            #pragma unroll
            for (int r = 0; r < 4; ++r) {
                float a0 = hv[0][r], a1 = hv[1][r];
                s_[r] = a0 + a1;
                q_[r] = a0 * a0 + a1 * a1;
            }
            #pragma unroll
            for (int off = 1; off < 16; off <<= 1) {
                #pragma unroll
                for (int r = 0; r < 4; ++r) {
                    s_[r] += __shfl_xor(s_[r], off, 64);
                    q_[r] += __shfl_xor(q_[r], off, 64);
                }
            }
            if (cc == 0) {
                #pragma unroll
                for (int r = 0; r < 4; ++r) {
                    sS[(q * 4 + r) * 8 + w] = s_[r];
                    sQ[(q * 4 + r) * 8 + w] = q_[r];
                }
            }
            __syncthreads();
            if (tid < 16) {
                float ts = 0.f, tq = 0.f;
                #pragma unroll
                for (int k = 0; k < 8; ++k) { ts += sS[tid * 8 + k]; tq += sQ[tid * 8 + k]; }
                float mu  = ts * (1.f / H1_);
                float var = tq * (1.f / H1_) - mu * mu;
                sMu[tid] = mu;
                sRs[tid] = 1.0f / sqrtf(var + 1e-5f);
            }
            __syncthreads();
            u32* s1 = myr1 + (size_t)lt * 4096;
            u16* s2 = myr2 + (size_t)lt * 4096;
            #pragma unroll
            for (int uu = 0; uu < 2; ++uu) {
                float gg = uu ? g1 : g0, bb = uu ? be1 : be0;
                int u = (w + 8 * uu) * 16 + cc;
                #pragma unroll
                for (int r = 0; r < 4; ++r) {
                    int m = q * 4 + r;
                    float hn = (hv[uu][r] - sMu[m]) * sRs[m] * gg + bb;
                    u16 a, b, c; split3(hn, a, b, c);
                    combA[m * 392 + 128 + u] = a;
                    combB[m * 392 + 128 + u] = b;
                    combC[m * 392 + 128 + u] = c;
                    __builtin_nontemporal_store(((u32)b << 16) | a, &s1[m * 256 + u]);
                    __builtin_nontemporal_store(c, &s2[m * 256 + u]);
                }
            }
            __syncthreads();
        }
        // store carry state for next chunk
        #pragma unroll
        for (int uu = 0; uu < 2; ++uu)
            #pragma unroll
            for (int r = 0; r < 4; ++r) {
                int m = q * 4 + r, u = (w + 8 * uu) * 16 + cc;
                __builtin_nontemporal_store(cst[uu][r], &c1s[(size_t)(b0 + m) * 256 + u]);
            }
        for (int i = tid; i < 4096; i += 512) {
            int row = i >> 8, col = i & 255;
            size_t g = (size_t)(b0 + row) * 256 + col;
            __builtin_nontemporal_store(combA[row * 392 + 128 + col], &h1a[g]);
            __builtin_nontemporal_store(combB[row * 392 + 128 + col], &h1b[g]);
            __builtin_nontemporal_store(combC[row * 392 + 128 + col], &h1c[g]);
        }
    } else {
        // ============ PHASE 2 : layer 2, chunk [t2, t2+Tc) ============
        const int t2 = t0 - Tc;
        if (t2 < 0) return;
        const int tile = bid - 32, b0 = tile * 16;

        frag8 wregH2[4][6];   // hi-weights kf 0..5 resident
        #pragma unroll
        for (int k = 0; k < 4; ++k) {
            int nt = w + 8 * k;
            #pragma unroll
            for (int kf = 0; kf < 6; ++kf)
                wregH2[k][kf] = *(const frag8*)&w2a[(((size_t)nt * 12 + kf) * 64 + lane) * 8];
        }
        float bz[4];
        #pragma unroll
        for (int k = 0; k < 4; ++k) {
            int n = (w + 8 * k) * 16 + cc;
            const float* bp = (n < 128) ? bf2 : (n < 256) ? bi2 : (n < 384) ? bg2 : bo2;
            bz[k] = bp[n & 127];
        }
        const int u = w * 16 + cc;
        const float gg2 = gamma2[u], bb2 = beta2[u];

        if (t2 == 0) {
            for (int i = tid; i < 2048; i += 512) {
                int row = i >> 7, col = i & 127;
                combA[row * 392 + 256 + col] = 0;
                combB[row * 392 + 256 + col] = 0;
                combC[row * 392 + 256 + col] = 0;
            }
        } else {
            for (int i = tid; i < 2048; i += 512) {
                int row = i >> 7, col = i & 127;
                size_t g = (size_t)(b0 + row) * 128 + col;
                combA[row * 392 + 256 + col] = __builtin_nontemporal_load(&h2a[g]);
                combB[row * 392 + 256 + col] = __builtin_nontemporal_load(&h2b[g]);
                combC[row * 392 + 256 + col] = __builtin_nontemporal_load(&h2c[g]);
            }
        }
        float cst[4];
        #pragma unroll
        for (int r = 0; r < 4; ++r) {
            int m = q * 4 + r;
            cst[r] = (t2 == 0) ? 0.f
                : __builtin_nontemporal_load(&c2s[(size_t)(b0 + m) * 128 + u]);
        }
        __syncthreads();

        const int par = (t2 / Tc) & 1;
        const u32* myr1 = ring1 + (((size_t)par * 32 + tile) * Tc) * 4096;
        const u16* myr2 = ring2 + (((size_t)par * 32 + tile) * Tc) * 4096;

        for (int lt = 0; lt < Tc; ++lt) {
            const int t = t2 + lt;
            {   // ring slot -> comb cols [0,256)
                const u32* s1 = myr1 + (size_t)lt * 4096;
                const u16* s2 = myr2 + (size_t)lt * 4096;
                int row = tid >> 5, cb = (tid & 31) * 8;
                #pragma unroll
                for (int d = 0; d < 2; ++d) {
                    uv4 v = __builtin_nontemporal_load((const uv4*)&s1[row * 256 + cb + d * 4]);
                    #pragma unroll
                    for (int e = 0; e < 4; ++e) {
                        combA[row * 392 + cb + d * 4 + e] = (u16)(v[e] & 0xffffu);
                        combB[row * 392 + cb + d * 4 + e] = (u16)(v[e] >> 16);
                    }
                }
                uv4 v2 = __builtin_nontemporal_load((const uv4*)&s2[row * 256 + cb]);
                *(uv4*)&combC[row * 392 + cb] = v2;
            }
            __syncthreads();

            facc4 g0a[4], g1a[4], g2a[4];
            #pragma unroll
            for (int k = 0; k < 4; ++k) {
                g0a[k] = (facc4){0.f,0.f,0.f,0.f};
                g1a[k] = (facc4){0.f,0.f,0.f,0.f};
                g2a[k] = (facc4){0.f,0.f,0.f,0.f};
            }
            #pragma unroll
            for (int kf = 0; kf < 12; ++kf) {
                frag8 aH = *(frag8*)&combA[cc * 392 + kf * 32 + q * 8];
                frag8 aM = *(frag8*)&combB[cc * 392 + kf * 32 + q * 8];
                frag8 aL = *(frag8*)&combC[cc * 392 + kf * 32 + q * 8];
                #pragma unroll
                for (int k = 0; k < 4; ++k) {
                    size_t base = (((size_t)(w + 8 * k) * 12 + kf) * 64 + lane) * 8;
                    frag8 bH = (kf < 6) ? wregH2[k][kf] : *(const frag8*)&w2a[base];
                    frag8 bM = *(const frag8*)&w2b[base];
                    frag8 bL = *(const frag8*)&w2c[base];
                    g0a[k] = __builtin_amdgcn_mfma_f32_16x16x32_f16(aH, bH, g0a[k], 0, 0, 0);
                    g1a[k] = __builtin_amdgcn_mfma_f32_16x16x32_f16(aH, bM, g1a[k], 0, 0, 0);
                    g1a[k] = __builtin_amdgcn_mfma_f32_16x16x32_f16(aM, bH, g1a[k], 0, 0, 0);
                    g2a[k] = __builtin_amdgcn_mfma_f32_16x16x32_f16(aH, bL, g2a[k], 0, 0, 0);
                    g2a[k] = __builtin_amdgcn_mfma_f32_16x16x32_f16(aM, bM, g2a[k], 0, 0, 0);
                    g2a[k] = __builtin_amdgcn_mfma_f32_16x16x32_f16(aL, bH, g2a[k], 0, 0, 0);
                }
            }
            float hv[4];
            #pragma unroll
            for (int r = 0; r < 4; ++r) {
                float zf = g0a[0][r] + g1a[0][r]*ISC1 + g2a[0][r]*ISC2 + bz[0];
                float zi = g0a[1][r] + g1a[1][r]*ISC1 + g2a[1][r]*ISC2 + bz[1];
                float zg = g0a[2][r] + g1a[2][r]*ISC1 + g2a[2][r]*ISC2 + bz[2];
                float zo = g0a[3][r] + g1a[3][r]*ISC1 + g2a[3][r]*ISC2 + bz[3];
                float c  = sigm_(zf) * cst[r] + sigm_(zi) * tanhf(zg);
                cst[r] = c;
                hv[r]  = sigm_(zo) * tanhf(c);
            }
            float s_[4], q_[4];
            #pragma unroll
            for (int r = 0; r < 4; ++r) { s_[r] = hv[r]; q_[r] = hv[r] * hv[r]; }
            #pragma unroll
            for (int off = 1; off < 16; off <<= 1) {
                #pragma unroll
                for (int r = 0; r < 4; ++r) {
                    s_[r] += __shfl_xor(s_[r], off, 64);
                    q_[r] += __shfl_xor(q_[r], off, 64);
                }
            }
            if (cc == 0) {
                #pragma unroll
                for (int r = 0; r < 4; ++r) {
                    sS[(q * 4 + r) * 8 + w] = s_[r];
                    sQ[(q * 4 + r) * 8 + w] = q_[r];
                }
            }
            __syncthreads();
            if (tid < 16) {
                float ts = 0.f, tq = 0.f;
                #pragma unroll
                for (int k = 0; k < 8; ++k) { ts += sS[tid * 8 + k]; tq += sQ[tid * 8 + k]; }
                float mu  = ts * (1.f / H2_);
                float var = tq * (1.f / H2_) - mu * mu;
                sMu[tid] = mu;
                sRs[tid] = 1.0f / sqrtf(var + 1e-5f);
            }
            __syncthreads();
            #pragma unroll
            for (int r = 0; r < 4; ++r) {
                int m = q * 4 + r;
                float hn = (hv[r] - sMu[m]) * sRs[m] * gg2 + bb2;
                u16 a, b, c; split3(hn, a, b, c);
                combA[m * 392 + 256 + u] = a;
                combB[m * 392 + 256 + u] = b;
                combC[m * 392 + 256 + u] = c;
                if (t == S_ - 1) out[(size_t)(b0 + m) * H2_ + u] = hn;
            }
            __syncthreads();
        }
        #pragma unroll
        for (int r = 0; r < 4; ++r) {
            int m = q * 4 + r;
            __builtin_nontemporal_store(cst[r], &c2s[(size_t)(b0 + m) * 128 + u]);
        }
        for (int i = tid; i < 2048; i += 512) {
            int row = i >> 7, col = i & 127;
            size_t g = (size_t)(b0 + row) * 128 + col;
            __builtin_nontemporal_store(combA[row * 392 + 256 + col], &h2a[g]);
            __builtin_nontemporal_store(combB[row * 392 + 256 + col], &h2b[g]);
            __builtin_nontemporal_store(combC[row * 392 + 256 + col], &h2c[g]);
        }
    }
}

extern "C" void kernel_launch(void* const* d_in, const int* in_sizes, int n_in,
                              void* d_out, int out_size, void* d_ws, size_t ws_size,
                              hipStream_t stream) {
    const float* x      = (const float*)d_in[0];
    const float* Wf1    = (const float*)d_in[1];
    const float* Wi1    = (const float*)d_in[2];
    const float* Wg1    = (const float*)d_in[3];
    const float* Wo1    = (const float*)d_in[4];
    const float* bf1    = (const float*)d_in[5];
    const float* bi1    = (const float*)d_in[6];
    const float* bg1    = (const float*)d_in[7];
    const float* bo1    = (const float*)d_in[8];
    const float* Wf2    = (const float*)d_in[9];
    const float* Wi2    = (const float*)d_in[10];
    const float* Wg2    = (const float*)d_in[11];
    const float* Wo2    = (const float*)d_in[12];
    const float* bf2    = (const float*)d_in[13];
    const float* bi2    = (const float*)d_in[14];
    const float* bg2    = (const float*)d_in[15];
    const float* bo2    = (const float*)d_in[16];
    const float* gamma1 = (const float*)d_in[17];
    const float* beta1  = (const float*)d_in[18];
    const float* gamma2 = (const float*)d_in[19];
    const float* beta2  = (const float*)d_in[20];

    char* ws = (char*)d_ws;
    u16*   w1a = (u16*)ws;
    u16*   w1b = (u16*)(ws + 786432);
    u16*   w1c = (u16*)(ws + 1572864);
    u16*   w2a = (u16*)(ws + 2359296);
    u16*   w2b = (u16*)(ws + 2752512);
    u16*   w2c = (u16*)(ws + 3145728);
    float* c1s = (float*)(ws + 3538944);
    u16*   h1a = (u16*)(ws + 4063232);
    u16*   h1b = (u16*)(ws + 4325376);
    u16*   h1c = (u16*)(ws + 4587520);
    float* c2s = (float*)(ws + 4849664);
    u16*   h2a = (u16*)(ws + 5111808);
    u16*   h2b = (u16*)(ws + 5242880);
    u16*   h2c = (u16*)(ws + 5373952);

    // ring: ring1 (u32) then ring2 (u16), each [2][32][Tc][16][256]
    int Tc = 2;
    const int cands[6] = {64, 32, 16, 8, 4, 2};
    for (int i = 0; i < 6; ++i) {
        size_t need = 5505024 + (size_t)cands[i] * (1048576 + 524288);
        if (need <= ws_size) { Tc = cands[i]; break; }
    }
    u32* ring1 = (u32*)(ws + 5505024);
    u16* ring2 = (u16*)(ws + 5505024 + (size_t)Tc * 1048576);
    const int nch = S_ / Tc;

    prep_weights<<<2304, 256, 0, stream>>>(Wf1, Wi1, Wg1, Wo1, Wf2, Wi2, Wg2, Wo2,
                                           w1a, w1b, w1c, w2a, w2b, w2c);

    // dispatch k: blocks 0..31 run layer-1 chunk k; blocks 32..63 run layer-2 chunk k-1.
    // Layer-2 reads ring data written by the PREVIOUS dispatch (parity double-buffer) —
    // cross-dispatch coherence is guaranteed on a stream; zero in-kernel cross-block sync.
    for (int k = 0; k <= nch; ++k) {
        lstm_chunk<<<64, 512, 38784, stream>>>(
            x, bf1, bi1, bg1, bo1, bf2, bi2, bg2, bo2,
            gamma1, beta1, gamma2, beta2,
            w1a, w1b, w1c, w2a, w2b, w2c, ring1, ring2,
            c1s, h1a, h1b, h1c, c2s, h2a, h2b, h2c,
            k * Tc, Tc, (float*)d_out);
    }
}